// Round 11
// baseline (227.524 us; speedup 1.0000x reference)
//
#include <hip/hip_runtime.h>

// ---------------------------------------------------------------------------
// SpectralMamba fused kernel (MI355X / gfx950) — R11: 64-row tile, 2048
// blocks, 32x32x16 MFMAs for GEMM1/3/4, 128-VGPR class.
//
// Key insight (R8/R9): residency is pinned at 2 blocks/CU for 512-thread
// blocks regardless of LDS -> 4 waves/SIMD -> 128 VGPR is free.
// __launch_bounds__(512,2) grants it; straight-line body (loops spill, R5-R7).
//
// 32x32x16 operand mappings (same pack formats as 16x16x32!):
//   A (weights [k/8][col][k%8]): lane l reads col=base+(l&31), k8=k0/8+(l>>5)
//   B (act [j/8][m][j%8]):       lane l reads m=base+(l&31),  k8=k0/8+(l>>5)
//   C/D: col(=m)=l&31, row(=outcol)=(r&3)+8*(r>>2)+4*(l>>5)  [guide m74/m101]
// GEMM3: K=16 == one 32x32x16 step -> no zero padding, DTP init deleted.
// ---------------------------------------------------------------------------

typedef _Float16 f16x8 __attribute__((ext_vector_type(8)));
typedef _Float16 f16x2 __attribute__((ext_vector_type(2)));
typedef __fp16 fp16x2b __attribute__((ext_vector_type(2)));   // builtin return type
typedef float f32x4 __attribute__((ext_vector_type(4)));
typedef float f32x16 __attribute__((ext_vector_type(16)));

#define MFMA16(a,b,c) __builtin_amdgcn_mfma_f32_16x16x32_f16((a),(b),(c),0,0,0)
#define MFMA32(a,b,c) __builtin_amdgcn_mfma_f32_32x32x16_f16((a),(b),(c),0,0,0)

// workspace layout (bytes): packs are [k/8][outcol][k%8] f16 = W[k][outcol]
#define WPIN_OFF   0u        // 32k8 x 1024 x 8 f16 = 512 KB (xi half pre-scaled by conv_w[:,3])
#define WPOUT_OFF  524288u   // 64k8 x 256  x 8     = 256 KB
#define WPXP_OFF   786432u   // 64k8 x 48   x 8     = 48 KB
#define WPDT_OFF   835584u   // 2k8  x 512  x 8     = 16 KB (K=16 exact, no pad)

// LDS layout (bytes). U (phases 1-2) union'd with XC (phases >=2.5).
#define U_OFF     0          // u pack:  [32 k8][64 m][8] f16 = 32 KB
#define XC_OFF    0          // xc/y pack: [64 j8][64 m][8] f16 = 64 KB
#define DTP_OFF   65536      // dt pack: [2 k8][64 m][8] f16 = 2 KB
#define BC_OFF    67584      // bc: [64] f32 = 256 B
#define LDS_BYTES 67840

__device__ __forceinline__ unsigned short f16bits(float f) {
  union { _Float16 h; unsigned short u; } c; c.h = (_Float16)f; return c.u;
}
__device__ __forceinline__ unsigned pk2(float a, float b) {
  union { fp16x2b h; unsigned u; } c;
  c.h = __builtin_amdgcn_cvt_pkrtz(a, b);
  return c.u;
}
__device__ __forceinline__ f16x2 upk(unsigned u) {
  union { unsigned u; f16x2 h; } c; c.u = u; return c.h;
}
__device__ __forceinline__ float siluf(float t) {
  return t * __builtin_amdgcn_rcpf(1.f + __expf(-t));
}
__device__ __forceinline__ float softplusf(float t) {
  return fmaxf(t, 0.f) + __logf(1.f + __expf(-fabsf(t)));
}

// pack fp32 [K][N] weight -> f16 fragment layout [KB][N][8], zero-pad k>=K
__global__ void pack_w_kernel(const float* __restrict__ src,
                              unsigned short* __restrict__ dst,
                              int K, int N, int KB) {
  int t = blockIdx.x * 256 + threadIdx.x;
  if (t >= KB * N * 8) return;
  int ke = t & 7;
  int n  = (t >> 3) % N;
  int kb = t / (N * 8);
  int k  = kb * 8 + ke;
  float v = (k < K) ? src[k * N + n] : 0.f;
  dst[t] = f16bits(v);
}

// pack W_in with conv_w[:,3] folded into the xi half (cols 0..511)
__global__ void pack_win_kernel(const float* __restrict__ W_in,
                                const float* __restrict__ conv_w,
                                unsigned short* __restrict__ dst) {
  int t = blockIdx.x * 256 + threadIdx.x;   // 32*1024*8 = 262144 total
  int ke = t & 7;
  int n  = (t >> 3) & 1023;
  int kb = t >> 13;
  float v = W_in[(kb * 8 + ke) * 1024 + n];
  if (n < 512) v *= conv_w[n * 4 + 3];
  dst[t] = f16bits(v);
}

__global__ __launch_bounds__(512, 2) void mamba_fused_kernel(
    const float* __restrict__ x,
    const float* __restrict__ conv_b,
    const float* __restrict__ b_dt,
    const float* __restrict__ Dvec,
    float* __restrict__ out,
    const char* __restrict__ ws)
{
  __shared__ __align__(16) char smem[LDS_BYTES];

  const int tid  = threadIdx.x;
  const int wv   = tid >> 6;     // wave 0..7
  const int l    = tid & 63;
  const int lrow = l & 15;       // 16x16 indices (GEMM2)
  const int lhi  = l >> 4;
  const int l31  = l & 31;       // 32x32 indices
  const int lh   = l >> 5;

  const int wg   = blockIdx.x;
  const int w0   = (wg & 1) << 6;
  const int hb   = wg >> 1;
  const int h    = hb & 127;
  const int bidx = hb >> 7;

  const f16x8* wp_in  = (const f16x8*)(ws + WPIN_OFF);
  const f16x8* wp_out = (const f16x8*)(ws + WPOUT_OFF);
  const f16x8* wp_xp  = (const f16x8*)(ws + WPXP_OFF);
  const f16x8* wp_dt  = (const f16x8*)(ws + WPDT_OFF);

  // ---------------- phase 1: load u tile -> LDS B-pack [c/8][m][c%8] -------
  {
    const float* xb = x + ((long)(bidx * 256) * 128 + h) * 128 + w0;
    #pragma unroll
    for (int i = 0; i < 4; ++i) {
      int cg = i * 8 + wv;             // channel group 0..31 (8 channels each)
      float f[8];
      #pragma unroll
      for (int j = 0; j < 8; ++j)
        f[j] = __builtin_nontemporal_load(xb + (long)(cg * 8 + j) * 16384 + l);
      uint4 pk;
      pk.x = pk2(f[0], f[1]); pk.y = pk2(f[2], f[3]);
      pk.z = pk2(f[4], f[5]); pk.w = pk2(f[6], f[7]);
      *(uint4*)(smem + U_OFF + (cg * 64 + l) * 16) = pk;
    }
  }
  __syncthreads();

  unsigned sz_pk[2][2][4][2];   // silu(z) f16 pairs: [ct][rt][q4][p]
  f32x16 accx[2][2];            // hf0 (xi) accumulators, live across barrier

  // ---------------- phase 2: GEMM1 xz^T = W_in^T @ u^T (32x32x16) ----------
  // hf=1 (z) first -> sz regs; hf=0 (xi) second -> accx, epilogued after the
  // barrier (U/XC union: no XC write until all U reads complete).
  {
    // ---- hf = 1: z columns ----
    {
      f32x16 acc[2][2];
      #pragma unroll
      for (int ct = 0; ct < 2; ++ct)
        #pragma unroll
        for (int rt = 0; rt < 2; ++rt)
          #pragma unroll
          for (int e = 0; e < 16; ++e) acc[ct][rt][e] = 0.f;
      const int cb = 512 + wv * 64;
      __builtin_amdgcn_s_setprio(1);
      #pragma unroll
      for (int ks = 0; ks < 16; ++ks) {
        f16x8 b[2];
        #pragma unroll
        for (int rt = 0; rt < 2; ++rt)
          b[rt] = *(const f16x8*)(smem + U_OFF + ((2 * ks + lh) * 64 + rt * 32 + l31) * 16);
        f16x8 a[2];
        #pragma unroll
        for (int ct = 0; ct < 2; ++ct)
          a[ct] = wp_in[(2 * ks + lh) * 1024 + cb + ct * 32 + l31];
        #pragma unroll
        for (int ct = 0; ct < 2; ++ct)
          #pragma unroll
          for (int rt = 0; rt < 2; ++rt)
            acc[ct][rt] = MFMA32(a[ct], b[rt], acc[ct][rt]);
      }
      __builtin_amdgcn_s_setprio(0);
      #pragma unroll
      for (int ct = 0; ct < 2; ++ct)
        #pragma unroll
        for (int rt = 0; rt < 2; ++rt)
          #pragma unroll
          for (int q4 = 0; q4 < 4; ++q4) {
            float s0 = siluf(acc[ct][rt][4 * q4 + 0]);
            float s1 = siluf(acc[ct][rt][4 * q4 + 1]);
            float s2 = siluf(acc[ct][rt][4 * q4 + 2]);
            float s3 = siluf(acc[ct][rt][4 * q4 + 3]);
            sz_pk[ct][rt][q4][0] = pk2(s0, s1);
            sz_pk[ct][rt][q4][1] = pk2(s2, s3);
          }
    }
    // ---- hf = 0: xi columns (conv_w folded in pack, conv_b via C-in) ----
    {
      const int cb = wv * 64;
      #pragma unroll
      for (int ct = 0; ct < 2; ++ct) {
        #pragma unroll
        for (int q4 = 0; q4 < 4; ++q4) {
          f32x4 cb4 = *(const f32x4*)(conv_b + cb + ct * 32 + 8 * q4 + 4 * lh);
          #pragma unroll
          for (int i = 0; i < 4; ++i) {
            accx[ct][0][4 * q4 + i] = cb4[i];
            accx[ct][1][4 * q4 + i] = cb4[i];
          }
        }
      }
      __builtin_amdgcn_s_setprio(1);
      #pragma unroll
      for (int ks = 0; ks < 16; ++ks) {
        f16x8 b[2];
        #pragma unroll
        for (int rt = 0; rt < 2; ++rt)
          b[rt] = *(const f16x8*)(smem + U_OFF + ((2 * ks + lh) * 64 + rt * 32 + l31) * 16);
        f16x8 a[2];
        #pragma unroll
        for (int ct = 0; ct < 2; ++ct)
          a[ct] = wp_in[(2 * ks + lh) * 1024 + cb + ct * 32 + l31];
        #pragma unroll
        for (int ct = 0; ct < 2; ++ct)
          #pragma unroll
          for (int rt = 0; rt < 2; ++rt)
            accx[ct][rt] = MFMA32(a[ct], b[rt], accx[ct][rt]);
      }
      __builtin_amdgcn_s_setprio(0);
    }
  }
  __syncthreads();   // all U reads done; XC (union) may now be written

  // ---------------- phase 2.5: xc = silu(accx) -> LDS pack -----------------
  {
    #pragma unroll
    for (int ct = 0; ct < 2; ++ct) {
      const int jb8 = (wv * 64 + ct * 32) >> 3;
      #pragma unroll
      for (int rt = 0; rt < 2; ++rt)
        #pragma unroll
        for (int q4 = 0; q4 < 4; ++q4) {
          float s0 = siluf(accx[ct][rt][4 * q4 + 0]);
          float s1 = siluf(accx[ct][rt][4 * q4 + 1]);
          float s2 = siluf(accx[ct][rt][4 * q4 + 2]);
          float s3 = siluf(accx[ct][rt][4 * q4 + 3]);
          uint2 w2; w2.x = pk2(s0, s1); w2.y = pk2(s2, s3);
          *(uint2*)(smem + XC_OFF + ((jb8 + q4) * 64 + rt * 32 + l31) * 16 + lh * 8) = w2;
        }
    }
  }
  __syncthreads();

  // ---------------- phase 3: GEMM2 dbc^T = W_xproj^T @ xc^T (16x16x32) -----
  // waves 0-3: Bm & Cm tiles (mt=wv) + in-register bc reduce
  // waves 4-7: dt tile (mt=wv-4) -> DTP pack
  {
    if (wv < 4) {
      const int mt = wv;
      f32x4 accB = {0.f,0.f,0.f,0.f}, accC = {0.f,0.f,0.f,0.f};
      #pragma unroll
      for (int s = 0; s < 16; ++s) {
        f16x8 bx = *(const f16x8*)(smem + XC_OFF + ((s * 4 + lhi) * 64 + mt * 16 + lrow) * 16);
        f16x8 aB = wp_xp[(s * 4 + lhi) * 48 + 16 + lrow];
        f16x8 aC = wp_xp[(s * 4 + lhi) * 48 + 32 + lrow];
        accB = MFMA16(aB, bx, accB);
        accC = MFMA16(aC, bx, accC);
      }
      float sbc = accB[0]*accC[0] + accB[1]*accC[1] + accB[2]*accC[2] + accB[3]*accC[3];
      sbc += __shfl_xor(sbc, 16);
      sbc += __shfl_xor(sbc, 32);
      if (lhi == 0)
        *(float*)(smem + BC_OFF + (mt * 16 + lrow) * 4) = sbc;
    } else {
      const int mt = wv - 4;
      f32x4 accD = {0.f,0.f,0.f,0.f};
      #pragma unroll
      for (int s = 0; s < 16; ++s) {
        f16x8 bx = *(const f16x8*)(smem + XC_OFF + ((s * 4 + lhi) * 64 + mt * 16 + lrow) * 16);
        f16x8 aD = wp_xp[(s * 4 + lhi) * 48 + lrow];
        accD = MFMA16(aD, bx, accD);
      }
      const int p0 = lhi * 4;
      uint2 w2; w2.x = pk2(accD[0], accD[1]); w2.y = pk2(accD[2], accD[3]);
      *(uint2*)(smem + DTP_OFF + ((p0 >> 3) * 64 + mt * 16 + lrow) * 16 + (p0 & 7) * 2) = w2;
    }
  }
  __syncthreads();

  // ------- phase 4: GEMM3 delta^T = W_dt^T @ dt^T (32x32x16, K=16 exact) ---
  // y = (softplus(delta)*bc + D) * xc * sz, written in-place over xc in XC.
  {
    f16x8 b3[2];
    #pragma unroll
    for (int rt = 0; rt < 2; ++rt)
      b3[rt] = *(const f16x8*)(smem + DTP_OFF + (lh * 64 + rt * 32 + l31) * 16);
    float bcm[2];
    #pragma unroll
    for (int rt = 0; rt < 2; ++rt)
      bcm[rt] = *(const float*)(smem + BC_OFF + (rt * 32 + l31) * 4);
    #pragma unroll
    for (int ct = 0; ct < 2; ++ct) {
      const int oc0 = wv * 64 + ct * 32;
      f16x8 a3 = wp_dt[lh * 512 + oc0 + l31];
      f32x16 cin;
      f32x4 dv4[4];
      #pragma unroll
      for (int q4 = 0; q4 < 4; ++q4) {
        f32x4 bd = *(const f32x4*)(b_dt + oc0 + 8 * q4 + 4 * lh);
        #pragma unroll
        for (int i = 0; i < 4; ++i) cin[4 * q4 + i] = bd[i];
        dv4[q4] = *(const f32x4*)(Dvec + oc0 + 8 * q4 + 4 * lh);
      }
      #pragma unroll
      for (int rt = 0; rt < 2; ++rt) {
        f32x16 d = MFMA32(a3, b3[rt], cin);
        #pragma unroll
        for (int q4 = 0; q4 < 4; ++q4) {
          char* xaddr = smem + XC_OFF + (((oc0 >> 3) + q4) * 64 + rt * 32 + l31) * 16 + lh * 8;
          uint2 xcw = *(uint2*)xaddr;
          uint2 yw;
          #pragma unroll
          for (int p = 0; p < 2; ++p) {
            f16x2 xv = upk(p == 0 ? xcw.x : xcw.y);
            f16x2 zv = upk(sz_pk[ct][rt][q4][p]);
            f16x2 pr = xv * zv;                       // v_pk_mul_f16
            float d0 = softplusf(d[4 * q4 + 2 * p]);
            float d1 = softplusf(d[4 * q4 + 2 * p + 1]);
            float y0 = (d0 * bcm[rt] + dv4[q4][2 * p])     * (float)pr[0];
            float y1 = (d1 * bcm[rt] + dv4[q4][2 * p + 1]) * (float)pr[1];
            unsigned u = pk2(y0, y1);
            if (p == 0) yw.x = u; else yw.y = u;
          }
          *(uint2*)xaddr = yw;
        }
      }
    }
  }
  __syncthreads();

  // ---------------- phase 5: GEMM4 out^T = W_out^T @ y^T (32x32x16) --------
  {
    f32x16 acc4[2];
    #pragma unroll
    for (int rt = 0; rt < 2; ++rt)
      #pragma unroll
      for (int e = 0; e < 16; ++e) acc4[rt][e] = 0.f;
    __builtin_amdgcn_s_setprio(1);
    #pragma unroll
    for (int ks = 0; ks < 32; ++ks) {
      f16x8 by[2];
      #pragma unroll
      for (int rt = 0; rt < 2; ++rt)
        by[rt] = *(const f16x8*)(smem + XC_OFF + ((2 * ks + lh) * 64 + rt * 32 + l31) * 16);
      f16x8 aw = wp_out[(2 * ks + lh) * 256 + wv * 32 + l31];
      #pragma unroll
      for (int rt = 0; rt < 2; ++rt)
        acc4[rt] = MFMA32(aw, by[rt], acc4[rt]);
    }
    __builtin_amdgcn_s_setprio(0);
    // ch = wv*32 + 8*q4 + 4*lh + i ; m = rt*32 + l31 -> 2x128B segments/store
    const long obase = (long)(bidx * 256 + wv * 32 + 4 * lh) * 16384 + h * 128 + w0 + l31;
    #pragma unroll
    for (int rt = 0; rt < 2; ++rt)
      #pragma unroll
      for (int q4 = 0; q4 < 4; ++q4)
        #pragma unroll
        for (int i = 0; i < 4; ++i)
          __builtin_nontemporal_store(acc4[rt][4 * q4 + i],
              out + obase + (long)(8 * q4 + i) * 16384 + rt * 32);
  }
}

extern "C" void kernel_launch(void* const* d_in, const int* in_sizes, int n_in,
                              void* d_out, int out_size, void* d_ws, size_t ws_size,
                              hipStream_t stream) {
  const float* x       = (const float*)d_in[0];
  const float* W_in    = (const float*)d_in[1];
  const float* conv_w  = (const float*)d_in[2];
  const float* conv_b  = (const float*)d_in[3];
  const float* W_xproj = (const float*)d_in[4];
  const float* W_dt    = (const float*)d_in[5];
  const float* b_dt    = (const float*)d_in[6];
  // d_in[7] = A_log: unused by the reference's L=1 path
  const float* Dvec    = (const float*)d_in[8];
  const float* W_out   = (const float*)d_in[9];
  float* out = (float*)d_out;
  char* ws = (char*)d_ws;

  // pack weights to f16 fragment layout (once per launch, ~830 KB)
  pack_win_kernel<<<dim3(1024), dim3(256), 0, stream>>>(W_in, conv_w, (unsigned short*)(ws + WPIN_OFF));
  pack_w_kernel<<<dim3(512),  dim3(256), 0, stream>>>(W_out,   (unsigned short*)(ws + WPOUT_OFF), 512, 256, 64);
  pack_w_kernel<<<dim3(96),   dim3(256), 0, stream>>>(W_xproj, (unsigned short*)(ws + WPXP_OFF), 512, 48, 64);
  pack_w_kernel<<<dim3(32),   dim3(256), 0, stream>>>(W_dt,    (unsigned short*)(ws + WPDT_OFF), 16, 512, 2);

  // 2048 workgroups x 512 threads; each handles 64 rows (one half w-line)
  mamba_fused_kernel<<<dim3(2048), dim3(512), 0, stream>>>(
      x, conv_b, b_dt, Dvec, out, (const char*)ws);
}